// Round 1
// baseline (399.507 us; speedup 1.0000x reference)
//
#include <hip/hip_runtime.h>
#include <stdint.h>

// Problem: B=8, N=4096, C=512, H=8, D=64. fp32 in/out, bf16 MFMA internally.
#define NB 8
#define NN 4096
#define NC 512
#define NH 8

typedef __bf16 bf16x8 __attribute__((ext_vector_type(8)));
typedef float floatx4 __attribute__((ext_vector_type(4)));

__device__ __forceinline__ unsigned short f2bf(float f) {
  union { float f; unsigned u; } v; v.f = f;
  return (unsigned short)((v.u + 0x7fffu + ((v.u >> 16) & 1u)) >> 16);
}
__device__ __forceinline__ float bf2f(unsigned short s) {
  union { unsigned u; float f; } v; v.u = ((unsigned)s) << 16;
  return v.f;
}

// ---------- 1) fp32 -> bf16 convert (n % 4 == 0) ----------
__global__ __launch_bounds__(256) void k_convert(const float* __restrict__ src,
                                                 unsigned short* __restrict__ dst, int n) {
  int i = (blockIdx.x * 256 + threadIdx.x) * 4;
  if (i >= n) return;
  float4 v = *(const float4*)(src + i);
  ushort4 o;
  o.x = f2bf(v.x); o.y = f2bf(v.y); o.z = f2bf(v.z); o.w = f2bf(v.w);
  *(ushort4*)(dst + i) = o;
}

// ---------- 2) w_qkv [512][1536] fp32 -> wT [1536][512] bf16 (transpose) ----------
__global__ __launch_bounds__(256) void k_transpose_cvt(const float* __restrict__ w,
                                                       unsigned short* __restrict__ wt) {
  int id = blockIdx.x * 256 + threadIdx.x;   // 1536*512 threads
  int nn = id >> 9, kk = id & 511;
  wt[id] = f2bf(w[kk * 1536 + nn]);
}

// ---------- 3) qkv GEMM: [32768x512] @ [512x1536] + bias -> bf16 qkv ----------
// 128x128 tile, 4 waves (2x2 of 64x64), BK=64, mfma_f32_16x16x32_bf16.
__global__ __launch_bounds__(256) void k_gemm_qkv(const unsigned short* __restrict__ A,   // [32768][512]
                                                  const unsigned short* __restrict__ Bt,  // [1536][512]
                                                  const float* __restrict__ bias,         // [1536]
                                                  unsigned short* __restrict__ Cq) {      // [32768][1536]
  const int K = 512, LDA = 512, LDB = 512, LDC = 1536;
  int m0 = blockIdx.x * 128, n0 = blockIdx.y * 128;
  int tid = threadIdx.x;
  int lane = tid & 63, wave = tid >> 6;
  int wm = (wave & 1) * 64, wn = (wave >> 1) * 64;
  int quad = lane >> 4, rr = lane & 15;

  __shared__ __align__(16) unsigned short Als[128][72];  // +8 pad: conflict-free b128
  __shared__ __align__(16) unsigned short Bls[128][72];

  floatx4 acc[4][4];
#pragma unroll
  for (int i = 0; i < 4; i++)
#pragma unroll
    for (int j = 0; j < 4; j++) acc[i][j] = (floatx4){0.f, 0.f, 0.f, 0.f};

  int lrow = tid >> 3;        // 0..31
  int lcol = (tid & 7) * 8;   // 0..56

  for (int k0 = 0; k0 < K; k0 += 64) {
#pragma unroll
    for (int i = 0; i < 4; i++) {
      int row = lrow + 32 * i;
      uint4 va = *(const uint4*)(A + (size_t)(m0 + row) * LDA + k0 + lcol);
      *(uint4*)&Als[row][lcol] = va;
      uint4 vb = *(const uint4*)(Bt + (size_t)(n0 + row) * LDB + k0 + lcol);
      *(uint4*)&Bls[row][lcol] = vb;
    }
    __syncthreads();
#pragma unroll
    for (int kk = 0; kk < 64; kk += 32) {
      bf16x8 af[4], bfr[4];
#pragma unroll
      for (int mi = 0; mi < 4; mi++) af[mi] = *(const bf16x8*)&Als[wm + mi * 16 + rr][kk + quad * 8];
#pragma unroll
      for (int ni = 0; ni < 4; ni++) bfr[ni] = *(const bf16x8*)&Bls[wn + ni * 16 + rr][kk + quad * 8];
#pragma unroll
      for (int mi = 0; mi < 4; mi++)
#pragma unroll
        for (int ni = 0; ni < 4; ni++)
          acc[mi][ni] = __builtin_amdgcn_mfma_f32_16x16x32_bf16(af[mi], bfr[ni], acc[mi][ni], 0, 0, 0);
    }
    __syncthreads();
  }
#pragma unroll
  for (int ni = 0; ni < 4; ni++) {
    int col = n0 + wn + ni * 16 + rr;
    float bv = bias[col];
#pragma unroll
    for (int mi = 0; mi < 4; mi++) {
      int rbase = m0 + wm + mi * 16 + quad * 4;
#pragma unroll
      for (int r = 0; r < 4; r++)
        Cq[(size_t)(rbase + r) * LDC + col] = f2bf(acc[mi][ni][r] + bv);
    }
  }
}

// ---------- 4) per-token L2-norm factors for q and k ----------
__global__ __launch_bounds__(256) void k_norms(const unsigned short* __restrict__ QKV,
                                               float* __restrict__ fq, float* __restrict__ fk) {
  int id = blockIdx.x * 256 + threadIdx.x;  // 262144 = B*N*H
  int hh = id & 7;
  int bn = id >> 3;                          // b*4096+n
  const unsigned short* qrow = QKV + (size_t)bn * 1536 + hh * 64;
  float sq = 0.f, sk = 0.f;
#pragma unroll
  for (int j = 0; j < 64; j += 4) {
    ushort4 a = *(const ushort4*)(qrow + j);
    ushort4 b = *(const ushort4*)(qrow + 512 + j);
    float q0 = bf2f(a.x), q1 = bf2f(a.y), q2 = bf2f(a.z), q3 = bf2f(a.w);
    float k0 = bf2f(b.x), k1 = bf2f(b.y), k2 = bf2f(b.z), k3 = bf2f(b.w);
    sq += q0 * q0 + q1 * q1 + q2 * q2 + q3 * q3;
    sk += k0 * k0 + k1 * k1 + k2 * k2 + k3 * k3;
  }
  int b = bn >> 12, n = bn & 4095;
  int o = ((b * 8 + hh) << 12) + n;
  fq[o] = 0.125f * rsqrtf(fmaxf(sq, 1e-12f));  // * d^-0.5
  fk[o] = rsqrtf(fmaxf(sk, 1e-12f));
}

// ---------- 5) logits partials: per (b,h,chunk of 512 tokens) -> [64][64] ----------
__global__ __launch_bounds__(256) void k_attn(const unsigned short* __restrict__ QKV,
                                              const float* __restrict__ fq,
                                              const float* __restrict__ fk,
                                              float* __restrict__ logits_p) {
  int chunk = blockIdx.x;  // 0..7
  int hh = blockIdx.y, b = blockIdx.z;
  int t = threadIdx.x;
  __shared__ float qs[16][64], ks[16][64];
  int d = t & 63, g = t >> 6;
  float acc[16];
#pragma unroll
  for (int j = 0; j < 16; j++) acc[j] = 0.f;
  int n0 = chunk * 512;
  int bh = b * 8 + hh;
  for (int tk0 = 0; tk0 < 512; tk0 += 16) {
    __syncthreads();
#pragma unroll
    for (int i = 0; i < 4; i++) {
      int id = t + i * 256;
      int tok = id >> 6, dd = id & 63;
      int n = n0 + tk0 + tok;
      size_t base = (size_t)(b * 4096 + n) * 1536 + hh * 64 + dd;
      qs[tok][dd] = bf2f(QKV[base]) * fq[(bh << 12) + n];
      ks[tok][dd] = bf2f(QKV[base + 512]) * fk[(bh << 12) + n];
    }
    __syncthreads();
#pragma unroll 4
    for (int tok = 0; tok < 16; tok++) {
      float qv = qs[tok][d];
#pragma unroll
      for (int j = 0; j < 16; j++) acc[j] += qv * ks[tok][g * 16 + j];
    }
  }
  float* p = logits_p + ((size_t)bh * 8 + chunk) * 4096 + d * 64 + g * 16;
#pragma unroll
  for (int j = 0; j < 16; j++) p[j] = acc[j];
}

// ---------- 6) reduce partials over chunks ----------
__global__ __launch_bounds__(256) void k_reduce(const float* __restrict__ logits_p,
                                                float* __restrict__ logits) {
  int id = blockIdx.x * 256 + threadIdx.x;  // 262144
  int bh = id >> 12, r = id & 4095;
  const float* p = logits_p + (size_t)bh * 8 * 4096 + r;
  float s = 0.f;
#pragma unroll
  for (int c = 0; c < 8; c++) s += p[c * 4096];
  logits[id] = s;
}

// ---------- 7) softmax + M_b = blockdiag(attn) @ w_proj, store Mt[b][cout][c] bf16 ----------
__global__ __launch_bounds__(256) void k_softmax_m(const float* __restrict__ logits,
                                                   const float* __restrict__ wproj,
                                                   unsigned short* __restrict__ Mt) {
  int cc = blockIdx.x;  // cout chunk 0..3 (128 each)
  int hh = blockIdx.y, b = blockIdx.z;
  int t = threadIdx.x;
  __shared__ float ls[64][64];
  __shared__ float red[64][4];
  __shared__ float inv[64];
  const float* L = logits + (size_t)(b * 8 + hh) * 4096;
#pragma unroll
  for (int i = 0; i < 16; i++) {
    int id = t + i * 256;
    ls[id >> 6][id & 63] = L[id];
  }
  __syncthreads();
  int row = t >> 2, part = t & 3;
  float mx = -1e30f;
#pragma unroll
  for (int j = 0; j < 16; j++) mx = fmaxf(mx, ls[row][part * 16 + j]);
  red[row][part] = mx;
  __syncthreads();
  if (part == 0) inv[row] = fmaxf(fmaxf(red[row][0], red[row][1]), fmaxf(red[row][2], red[row][3]));
  __syncthreads();
  float rm = inv[row];
  float s = 0.f;
#pragma unroll
  for (int j = 0; j < 16; j++) {
    float e = __expf(ls[row][part * 16 + j] - rm);
    ls[row][part * 16 + j] = e;
    s += e;
  }
  red[row][part] = s;
  __syncthreads();
  if (part == 0) inv[row] = 1.0f / (red[row][0] + red[row][1] + red[row][2] + red[row][3]);
  __syncthreads();
  int cout = cc * 128 + (t & 127);
  for (int rep = 0; rep < 32; rep++) {
    int dd = (t >> 7) + rep * 2;
    float a = 0.f;
#pragma unroll 8
    for (int ee = 0; ee < 64; ee++) a += ls[dd][ee] * wproj[(hh * 64 + ee) * 512 + cout];
    a *= inv[dd];
    Mt[((size_t)b * 512 + cout) * 512 + hh * 64 + dd] = f2bf(a);
  }
}

// ---------- 8) out GEMM: per b, V[4096x512] @ M_b[512x512] + b_proj -> fp32 out ----------
__global__ __launch_bounds__(256) void k_gemm_out(const unsigned short* __restrict__ QKV,
                                                  const unsigned short* __restrict__ MtAll,
                                                  const float* __restrict__ bias,  // [512]
                                                  float* __restrict__ Out) {       // [32768][512]
  const int K = 512, LDA = 1536, LDB = 512, LDC = 512;
  int b = blockIdx.x >> 5;
  int m0 = (blockIdx.x & 31) * 128;
  int n0 = blockIdx.y * 128;
  const unsigned short* A = QKV + (size_t)b * NN * 1536 + 1024;  // v slice
  const unsigned short* Bt = MtAll + (size_t)b * 512 * 512;
  int tid = threadIdx.x;
  int lane = tid & 63, wave = tid >> 6;
  int wm = (wave & 1) * 64, wn = (wave >> 1) * 64;
  int quad = lane >> 4, rr = lane & 15;

  __shared__ __align__(16) unsigned short Als[128][72];
  __shared__ __align__(16) unsigned short Bls[128][72];

  floatx4 acc[4][4];
#pragma unroll
  for (int i = 0; i < 4; i++)
#pragma unroll
    for (int j = 0; j < 4; j++) acc[i][j] = (floatx4){0.f, 0.f, 0.f, 0.f};

  int lrow = tid >> 3;
  int lcol = (tid & 7) * 8;

  for (int k0 = 0; k0 < K; k0 += 64) {
#pragma unroll
    for (int i = 0; i < 4; i++) {
      int row = lrow + 32 * i;
      uint4 va = *(const uint4*)(A + (size_t)(m0 + row) * LDA + k0 + lcol);
      *(uint4*)&Als[row][lcol] = va;
      uint4 vb = *(const uint4*)(Bt + (size_t)(n0 + row) * LDB + k0 + lcol);
      *(uint4*)&Bls[row][lcol] = vb;
    }
    __syncthreads();
#pragma unroll
    for (int kk = 0; kk < 64; kk += 32) {
      bf16x8 af[4], bfr[4];
#pragma unroll
      for (int mi = 0; mi < 4; mi++) af[mi] = *(const bf16x8*)&Als[wm + mi * 16 + rr][kk + quad * 8];
#pragma unroll
      for (int ni = 0; ni < 4; ni++) bfr[ni] = *(const bf16x8*)&Bls[wn + ni * 16 + rr][kk + quad * 8];
#pragma unroll
      for (int mi = 0; mi < 4; mi++)
#pragma unroll
        for (int ni = 0; ni < 4; ni++)
          acc[mi][ni] = __builtin_amdgcn_mfma_f32_16x16x32_bf16(af[mi], bfr[ni], acc[mi][ni], 0, 0, 0);
    }
    __syncthreads();
  }
#pragma unroll
  for (int ni = 0; ni < 4; ni++) {
    int col = n0 + wn + ni * 16 + rr;
    float bv = bias[col];
#pragma unroll
    for (int mi = 0; mi < 4; mi++) {
      int rbase = m0 + wm + mi * 16 + quad * 4;
#pragma unroll
      for (int r = 0; r < 4; r++)
        Out[(size_t)b * NN * LDC + (size_t)(rbase + r) * LDC + col] = acc[mi][ni][r] + bv;
    }
  }
}

extern "C" void kernel_launch(void* const* d_in, const int* in_sizes, int n_in,
                              void* d_out, int out_size, void* d_ws, size_t ws_size,
                              hipStream_t stream) {
  const float* x      = (const float*)d_in[0];
  const float* w_qkv  = (const float*)d_in[1];
  const float* b_qkv  = (const float*)d_in[2];
  const float* w_proj = (const float*)d_in[3];
  const float* b_proj = (const float*)d_in[4];
  float* out = (float*)d_out;

  char* ws = (char*)d_ws;
  size_t off = 0;
  auto alloc = [&](size_t bytes) -> void* {
    void* p = ws + off;
    off += (bytes + 255) & ~(size_t)255;
    return p;
  };
  unsigned short* xb       = (unsigned short*)alloc((size_t)NB * NN * NC * 2);        // 33.5 MB
  unsigned short* wT       = (unsigned short*)alloc((size_t)1536 * 512 * 2);          // 1.5 MB
  unsigned short* qkvb     = (unsigned short*)alloc((size_t)NB * NN * 3 * NC * 2);    // 100.7 MB
  float*          fq       = (float*)alloc((size_t)NB * NH * NN * 4);                 // 1 MB
  float*          fk       = (float*)alloc((size_t)NB * NH * NN * 4);                 // 1 MB
  float*          logits_p = (float*)alloc((size_t)NB * NH * 8 * 4096 * 4);           // 8.4 MB
  float*          logits   = (float*)alloc((size_t)NB * NH * 4096 * 4);               // 1 MB
  unsigned short* Mt       = (unsigned short*)alloc((size_t)NB * 512 * 512 * 2);      // 4.2 MB

  k_convert<<<16384, 256, 0, stream>>>(x, xb, NB * NN * NC);
  k_transpose_cvt<<<3072, 256, 0, stream>>>(w_qkv, wT);
  k_gemm_qkv<<<dim3(256, 12), 256, 0, stream>>>(xb, wT, b_qkv, qkvb);
  k_norms<<<1024, 256, 0, stream>>>(qkvb, fq, fk);
  k_attn<<<dim3(8, 8, 8), 256, 0, stream>>>(qkvb, fq, fk, logits_p);
  k_reduce<<<1024, 256, 0, stream>>>(logits_p, logits);
  k_softmax_m<<<dim3(4, 8, 8), 256, 0, stream>>>(logits, w_proj, Mt);
  k_gemm_out<<<dim3(256, 4), 256, 0, stream>>>(qkvb, Mt, b_proj, out);
}

// Round 2
// 320.299 us; speedup vs baseline: 1.2473x; 1.2473x over previous
//
#include <hip/hip_runtime.h>
#include <stdint.h>

// Problem: B=8, N=4096, C=512, H=8, D=64. fp32 in/out, bf16 MFMA internally.
#define NB 8
#define NN 4096
#define NC 512
#define NH 8

typedef __bf16 bf16x8 __attribute__((ext_vector_type(8)));
typedef float floatx4 __attribute__((ext_vector_type(4)));

__device__ __forceinline__ unsigned short f2bf(float f) {
  union { float f; unsigned u; } v; v.f = f;
  return (unsigned short)((v.u + 0x7fffu + ((v.u >> 16) & 1u)) >> 16);
}
__device__ __forceinline__ float bf2f(unsigned short s) {
  union { unsigned u; float f; } v; v.u = ((unsigned)s) << 16;
  return v.f;
}
__device__ __forceinline__ float2 bfp2f(unsigned u) {
  union { unsigned x; float f; } lo, hi;
  lo.x = u << 16; hi.x = u & 0xffff0000u;
  return make_float2(lo.f, hi.f);
}

// async 16B global->LDS (DMA). LDS dest = wave-uniform base + lane*16.
__device__ __forceinline__ void async_ld16(void* lds, const void* g) {
  auto* gp = (const __attribute__((address_space(1))) unsigned int*)(uintptr_t)g;
  auto* lp = (__attribute__((address_space(3))) unsigned int*)(uintptr_t)lds;
  __builtin_amdgcn_global_load_lds(gp, lp, 16, 0, 0);
}

// ---------- 1) fp32 -> bf16 convert ----------
__global__ __launch_bounds__(256) void k_convert(const float* __restrict__ src,
                                                 unsigned short* __restrict__ dst, int n) {
  int i = (blockIdx.x * 256 + threadIdx.x) * 4;
  if (i >= n) return;
  float4 v = *(const float4*)(src + i);
  ushort4 o;
  o.x = f2bf(v.x); o.y = f2bf(v.y); o.z = f2bf(v.z); o.w = f2bf(v.w);
  *(ushort4*)(dst + i) = o;
}

// ---------- 2) w_qkv [512][1536] fp32 -> wT [1536][512] bf16 ----------
__global__ __launch_bounds__(256) void k_transpose_cvt(const float* __restrict__ w,
                                                       unsigned short* __restrict__ wt) {
  int id = blockIdx.x * 256 + threadIdx.x;
  int nn = id >> 9, kk = id & 511;
  wt[id] = f2bf(w[kk * 1536 + nn]);
}

// ---------- 3) qkv GEMM: [32768x512] @ [512x1536] + bias -> bf16 ----------
// 128x128 tile, 4 waves, BK=64. global_load_lds(16B) staging with XOR swizzle:
// LDS chunk (row, cg) holds global col-group cg^(row&7) -> bank-balanced ds_read_b128.
__global__ __launch_bounds__(256) void k_gemm_qkv(const unsigned short* __restrict__ A,   // [32768][512]
                                                  const unsigned short* __restrict__ Bt,  // [1536][512]
                                                  const float* __restrict__ bias,         // [1536]
                                                  unsigned short* __restrict__ Cq) {      // [32768][1536]
  const int K = 512, LDA = 512, LDB = 512, LDC = 1536;
  int m0 = blockIdx.x * 128, n0 = blockIdx.y * 128;
  int tid = threadIdx.x;
  int lane = tid & 63, w = tid >> 6;
  int wm = (w & 1) * 64, wn = (w >> 1) * 64;
  int quad = lane >> 4, rr = lane & 15;
  int r8 = lane >> 3;          // 0..7: row within the wave's 8-row chunk
  int cg = lane & 7;           // LDS col group (forced by lane order)
  int cgs = cg ^ r8;           // swizzled global col group
  const int swz = rr & 7;

  __shared__ __align__(16) unsigned short Als[128][64];
  __shared__ __align__(16) unsigned short Bls[128][64];

  floatx4 acc[4][4];
#pragma unroll
  for (int i = 0; i < 4; i++)
#pragma unroll
    for (int j = 0; j < 4; j++) acc[i][j] = (floatx4){0.f, 0.f, 0.f, 0.f};

  for (int k0 = 0; k0 < K; k0 += 64) {
#pragma unroll
    for (int i = 0; i < 4; i++) {
      int row = i * 32 + w * 8 + r8;
      async_ld16(&Als[i * 32 + w * 8][0], A + (size_t)(m0 + row) * LDA + k0 + cgs * 8);
      async_ld16(&Bls[i * 32 + w * 8][0], Bt + (size_t)(n0 + row) * LDB + k0 + cgs * 8);
    }
    __syncthreads();
#pragma unroll
    for (int kk = 0; kk < 64; kk += 32) {
      int gb = kk >> 3;
      bf16x8 af[4], bfr[4];
#pragma unroll
      for (int mi = 0; mi < 4; mi++)
        af[mi] = *(const bf16x8*)&Als[wm + mi * 16 + rr][(((gb + quad) ^ swz)) * 8];
#pragma unroll
      for (int ni = 0; ni < 4; ni++)
        bfr[ni] = *(const bf16x8*)&Bls[wn + ni * 16 + rr][(((gb + quad) ^ swz)) * 8];
#pragma unroll
      for (int mi = 0; mi < 4; mi++)
#pragma unroll
        for (int ni = 0; ni < 4; ni++)
          acc[mi][ni] = __builtin_amdgcn_mfma_f32_16x16x32_bf16(af[mi], bfr[ni], acc[mi][ni], 0, 0, 0);
    }
    __syncthreads();
  }
#pragma unroll
  for (int ni = 0; ni < 4; ni++) {
    int col = n0 + wn + ni * 16 + rr;
    float bv = bias[col];
#pragma unroll
    for (int mi = 0; mi < 4; mi++) {
      int rbase = m0 + wm + mi * 16 + quad * 4;
#pragma unroll
      for (int r = 0; r < 4; r++)
        Cq[(size_t)(rbase + r) * LDC + col] = f2bf(acc[mi][ni][r] + bv);
    }
  }
}

// ---------- 4) attn logits via MFMA, fused L2-norm. grid (chunk8, h8, b8) ----------
// Each wave: 128 tokens in 4 substeps of 32; stages scaled q^/k^ transposed
// into per-wave LDS tiles [64 dims][40 pad] bf16; 16 mfma per substep.
__global__ __launch_bounds__(256) void k_attn(const unsigned short* __restrict__ QKV,
                                              float* __restrict__ logits_p) {
  int chunk = blockIdx.x, hh = blockIdx.y, b = blockIdx.z;
  int tid = threadIdx.x, w = tid >> 6, l = tid & 63;
  int quad = l >> 4, rr = l & 15;

  __shared__ __align__(16) unsigned char smem[65536];
  unsigned short* qT = (unsigned short*)smem + w * 2560;              // 64*40 bf16, per wave
  unsigned short* kT = (unsigned short*)(smem + 20480) + w * 2560;
  float* ps = (float*)smem;                                           // reused after barrier

  floatx4 acc[4][4];
#pragma unroll
  for (int i = 0; i < 4; i++)
#pragma unroll
    for (int j = 0; j < 4; j++) acc[i][j] = (floatx4){0.f, 0.f, 0.f, 0.f};

  int t32 = l >> 1;            // token within 32
  int db = (l & 1) * 32;       // dim half

  for (int s = 0; s < 4; s++) {
    int n = chunk * 512 + w * 128 + s * 32 + t32;
    const unsigned short* basep = QKV + (size_t)(b * 4096 + n) * 1536 + hh * 64 + db;

    // ---- q: load 32 dims, sumsq, scale by d^-.5 * rsqrt, store transposed bf16
    float qf[32]; float sq = 0.f;
#pragma unroll
    for (int c = 0; c < 4; c++) {
      uint4 v = *(const uint4*)(basep + c * 8);
      unsigned uu[4] = {v.x, v.y, v.z, v.w};
#pragma unroll
      for (int e = 0; e < 4; e++) {
        float2 f = bfp2f(uu[e]);
        qf[c * 8 + e * 2] = f.x; qf[c * 8 + e * 2 + 1] = f.y;
        sq += f.x * f.x + f.y * f.y;
      }
    }
    sq += __shfl_xor(sq, 1);
    float scq = 0.125f * rsqrtf(fmaxf(sq, 1e-12f));
#pragma unroll
    for (int j = 0; j < 32; j++) qT[(db + j) * 40 + t32] = f2bf(qf[j] * scq);

    // ---- k: same with scale = rsqrt
    float sk = 0.f;
#pragma unroll
    for (int c = 0; c < 4; c++) {
      uint4 v = *(const uint4*)(basep + 512 + c * 8);
      unsigned uu[4] = {v.x, v.y, v.z, v.w};
#pragma unroll
      for (int e = 0; e < 4; e++) {
        float2 f = bfp2f(uu[e]);
        qf[c * 8 + e * 2] = f.x; qf[c * 8 + e * 2 + 1] = f.y;
        sk += f.x * f.x + f.y * f.y;
      }
    }
    sk += __shfl_xor(sk, 1);
    float sck = rsqrtf(fmaxf(sk, 1e-12f));
#pragma unroll
    for (int j = 0; j < 32; j++) kT[(db + j) * 40 + t32] = f2bf(qf[j] * sck);

    // ---- MFMA: attn[d][e] += sum over these 32 tokens
    bf16x8 af[4], bfr[4];
#pragma unroll
    for (int mi = 0; mi < 4; mi++) af[mi] = *(const bf16x8*)(qT + (mi * 16 + rr) * 40 + quad * 8);
#pragma unroll
    for (int ni = 0; ni < 4; ni++) bfr[ni] = *(const bf16x8*)(kT + (ni * 16 + rr) * 40 + quad * 8);
#pragma unroll
    for (int mi = 0; mi < 4; mi++)
#pragma unroll
      for (int ni = 0; ni < 4; ni++)
        acc[mi][ni] = __builtin_amdgcn_mfma_f32_16x16x32_bf16(af[mi], bfr[ni], acc[mi][ni], 0, 0, 0);
  }

  __syncthreads();  // all waves done with staging tiles; smem becomes ps
#pragma unroll
  for (int mi = 0; mi < 4; mi++)
#pragma unroll
    for (int ni = 0; ni < 4; ni++)
#pragma unroll
      for (int r = 0; r < 4; r++) {
        int d = mi * 16 + quad * 4 + r, e = ni * 16 + rr;
        ps[w * 4096 + d * 64 + e] = acc[mi][ni][r];
      }
  __syncthreads();
  float* outp = logits_p + ((size_t)(b * 8 + hh) * 8 + chunk) * 4096;
  for (int i = tid; i < 4096; i += 256)
    outp[i] = ps[i] + ps[4096 + i] + ps[8192 + i] + ps[12288 + i];
}

// ---------- 5) reduce partials over chunks ----------
__global__ __launch_bounds__(256) void k_reduce(const float* __restrict__ logits_p,
                                                float* __restrict__ logits) {
  int id = blockIdx.x * 256 + threadIdx.x;  // 262144
  int bh = id >> 12, r = id & 4095;
  const float* p = logits_p + (size_t)bh * 8 * 4096 + r;
  float s = 0.f;
#pragma unroll
  for (int c = 0; c < 8; c++) s += p[c * 4096];
  logits[id] = s;
}

// ---------- 6) softmax + M_b = blockdiag(attn) @ w_proj -> Mt[b][cout][c] bf16 ----------
__global__ __launch_bounds__(256) void k_softmax_m(const float* __restrict__ logits,
                                                   const float* __restrict__ wproj,
                                                   unsigned short* __restrict__ Mt) {
  int cc = blockIdx.x;  // cout chunk 0..3
  int hh = blockIdx.y, b = blockIdx.z;
  int t = threadIdx.x;
  __shared__ float ls[64][64];
  __shared__ float red[64][4];
  __shared__ float inv[64];
  const float* L = logits + (size_t)(b * 8 + hh) * 4096;
#pragma unroll
  for (int i = 0; i < 16; i++) {
    int id = t + i * 256;
    ls[id >> 6][id & 63] = L[id];
  }
  __syncthreads();
  int row = t >> 2, part = t & 3;
  float mx = -1e30f;
#pragma unroll
  for (int j = 0; j < 16; j++) mx = fmaxf(mx, ls[row][part * 16 + j]);
  red[row][part] = mx;
  __syncthreads();
  if (part == 0) inv[row] = fmaxf(fmaxf(red[row][0], red[row][1]), fmaxf(red[row][2], red[row][3]));
  __syncthreads();
  float rm = inv[row];
  float s = 0.f;
#pragma unroll
  for (int j = 0; j < 16; j++) {
    float e = __expf(ls[row][part * 16 + j] - rm);
    ls[row][part * 16 + j] = e;
    s += e;
  }
  red[row][part] = s;
  __syncthreads();
  if (part == 0) inv[row] = 1.0f / (red[row][0] + red[row][1] + red[row][2] + red[row][3]);
  __syncthreads();
  int cout = cc * 128 + (t & 127);
  for (int rep = 0; rep < 32; rep++) {
    int dd = (t >> 7) + rep * 2;
    float a = 0.f;
#pragma unroll 8
    for (int ee = 0; ee < 64; ee++) a += ls[dd][ee] * wproj[(hh * 64 + ee) * 512 + cout];
    a *= inv[dd];
    Mt[((size_t)b * 512 + cout) * 512 + hh * 64 + dd] = f2bf(a);
  }
}

// ---------- 7) out GEMM: per b, V[4096x512] @ M_b^T + b_proj -> fp32 ----------
__global__ __launch_bounds__(256) void k_gemm_out(const unsigned short* __restrict__ QKV,
                                                  const unsigned short* __restrict__ MtAll,
                                                  const float* __restrict__ bias,
                                                  float* __restrict__ Out) {
  const int K = 512, LDA = 1536, LDB = 512, LDC = 512;
  int b = blockIdx.x >> 5;
  int m0 = (blockIdx.x & 31) * 128;
  int n0 = blockIdx.y * 128;
  const unsigned short* A = QKV + (size_t)b * NN * 1536 + 1024;  // v slice
  const unsigned short* Bt = MtAll + (size_t)b * 512 * 512;
  int tid = threadIdx.x;
  int lane = tid & 63, w = tid >> 6;
  int wm = (w & 1) * 64, wn = (w >> 1) * 64;
  int quad = lane >> 4, rr = lane & 15;
  int r8 = lane >> 3, cg = lane & 7;
  int cgs = cg ^ r8;
  const int swz = rr & 7;

  __shared__ __align__(16) unsigned short Als[128][64];
  __shared__ __align__(16) unsigned short Bls[128][64];

  floatx4 acc[4][4];
#pragma unroll
  for (int i = 0; i < 4; i++)
#pragma unroll
    for (int j = 0; j < 4; j++) acc[i][j] = (floatx4){0.f, 0.f, 0.f, 0.f};

  for (int k0 = 0; k0 < K; k0 += 64) {
#pragma unroll
    for (int i = 0; i < 4; i++) {
      int row = i * 32 + w * 8 + r8;
      async_ld16(&Als[i * 32 + w * 8][0], A + (size_t)(m0 + row) * LDA + k0 + cgs * 8);
      async_ld16(&Bls[i * 32 + w * 8][0], Bt + (size_t)(n0 + row) * LDB + k0 + cgs * 8);
    }
    __syncthreads();
#pragma unroll
    for (int kk = 0; kk < 64; kk += 32) {
      int gb = kk >> 3;
      bf16x8 af[4], bfr[4];
#pragma unroll
      for (int mi = 0; mi < 4; mi++)
        af[mi] = *(const bf16x8*)&Als[wm + mi * 16 + rr][(((gb + quad) ^ swz)) * 8];
#pragma unroll
      for (int ni = 0; ni < 4; ni++)
        bfr[ni] = *(const bf16x8*)&Bls[wn + ni * 16 + rr][(((gb + quad) ^ swz)) * 8];
#pragma unroll
      for (int mi = 0; mi < 4; mi++)
#pragma unroll
        for (int ni = 0; ni < 4; ni++)
          acc[mi][ni] = __builtin_amdgcn_mfma_f32_16x16x32_bf16(af[mi], bfr[ni], acc[mi][ni], 0, 0, 0);
    }
    __syncthreads();
  }
#pragma unroll
  for (int ni = 0; ni < 4; ni++) {
    int col = n0 + wn + ni * 16 + rr;
    float bv = bias[col];
#pragma unroll
    for (int mi = 0; mi < 4; mi++) {
      int rbase = m0 + wm + mi * 16 + quad * 4;
#pragma unroll
      for (int r = 0; r < 4; r++)
        Out[(size_t)b * NN * LDC + (size_t)(rbase + r) * LDC + col] = acc[mi][ni][r] + bv;
    }
  }
}

extern "C" void kernel_launch(void* const* d_in, const int* in_sizes, int n_in,
                              void* d_out, int out_size, void* d_ws, size_t ws_size,
                              hipStream_t stream) {
  const float* x      = (const float*)d_in[0];
  const float* w_qkv  = (const float*)d_in[1];
  const float* b_qkv  = (const float*)d_in[2];
  const float* w_proj = (const float*)d_in[3];
  const float* b_proj = (const float*)d_in[4];
  float* out = (float*)d_out;

  char* ws = (char*)d_ws;
  size_t off = 0;
  auto alloc = [&](size_t bytes) -> void* {
    void* p = ws + off;
    off += (bytes + 255) & ~(size_t)255;
    return p;
  };
  unsigned short* xb       = (unsigned short*)alloc((size_t)NB * NN * NC * 2);
  unsigned short* wT       = (unsigned short*)alloc((size_t)1536 * 512 * 2);
  unsigned short* qkvb     = (unsigned short*)alloc((size_t)NB * NN * 3 * NC * 2);
  float*          logits_p = (float*)alloc((size_t)NB * NH * 8 * 4096 * 4);
  float*          logits   = (float*)alloc((size_t)NB * NH * 4096 * 4);
  unsigned short* Mt       = (unsigned short*)alloc((size_t)NB * 512 * 512 * 2);

  k_convert<<<16384, 256, 0, stream>>>(x, xb, NB * NN * NC);
  k_transpose_cvt<<<3072, 256, 0, stream>>>(w_qkv, wT);
  k_gemm_qkv<<<dim3(256, 12), 256, 0, stream>>>(xb, wT, b_qkv, qkvb);
  k_attn<<<dim3(8, 8, 8), 256, 0, stream>>>(qkvb, logits_p);
  k_reduce<<<1024, 256, 0, stream>>>(logits_p, logits);
  k_softmax_m<<<dim3(4, 8, 8), 256, 0, stream>>>(logits, w_proj, Mt);
  k_gemm_out<<<dim3(256, 4), 256, 0, stream>>>(qkvb, Mt, b_proj, out);
}

// Round 3
// 276.460 us; speedup vs baseline: 1.4451x; 1.1586x over previous
//
#include <hip/hip_runtime.h>
#include <stdint.h>

// Problem: B=8, N=4096, C=512, H=8, D=64. fp32 in/out, bf16 MFMA internally.
#define NB 8
#define NN 4096
#define NC 512
#define NH 8

typedef __bf16 bf16x8 __attribute__((ext_vector_type(8)));
typedef float floatx4 __attribute__((ext_vector_type(4)));

__device__ __forceinline__ unsigned short f2bf(float f) {
  union { float f; unsigned u; } v; v.f = f;
  return (unsigned short)((v.u + 0x7fffu + ((v.u >> 16) & 1u)) >> 16);
}
__device__ __forceinline__ float bf2f(unsigned short s) {
  union { unsigned u; float f; } v; v.u = ((unsigned)s) << 16;
  return v.f;
}
__device__ __forceinline__ float2 bfp2f(unsigned u) {
  union { unsigned x; float f; } lo, hi;
  lo.x = u << 16; hi.x = u & 0xffff0000u;
  return make_float2(lo.f, hi.f);
}

// async 16B global->LDS (DMA). LDS dest = wave-uniform base + lane*16.
__device__ __forceinline__ void async_ld16(void* lds, const void* g) {
  auto* gp = (const __attribute__((address_space(1))) unsigned int*)(uintptr_t)g;
  auto* lp = (__attribute__((address_space(3))) unsigned int*)(uintptr_t)lds;
  __builtin_amdgcn_global_load_lds(gp, lp, 16, 0, 0);
}

// ---------- 1) fp32 -> bf16 convert ----------
__global__ __launch_bounds__(256) void k_convert(const float* __restrict__ src,
                                                 unsigned short* __restrict__ dst, int n) {
  int i = (blockIdx.x * 256 + threadIdx.x) * 4;
  if (i >= n) return;
  float4 v = *(const float4*)(src + i);
  ushort4 o;
  o.x = f2bf(v.x); o.y = f2bf(v.y); o.z = f2bf(v.z); o.w = f2bf(v.w);
  *(ushort4*)(dst + i) = o;
}

// ---------- 2) w_qkv [512][1536] fp32 -> wT [1536][512] bf16, LDS tiled ----------
__global__ __launch_bounds__(256) void k_transpose_cvt(const float* __restrict__ w,
                                                       unsigned short* __restrict__ wt) {
  __shared__ float tile[64][65];
  int nn0 = blockIdx.x * 64, kk0 = blockIdx.y * 64;
  int t = threadIdx.x;
#pragma unroll
  for (int i = 0; i < 16; i++) {
    int id = t + i * 256;
    int r = id >> 6, c = id & 63;                 // r: kk offset, c: nn offset
    tile[c][r] = w[(size_t)(kk0 + r) * 1536 + nn0 + c];
  }
  __syncthreads();
#pragma unroll
  for (int i = 0; i < 16; i++) {
    int id = t + i * 256;
    int rn = id >> 6, ck = id & 63;               // rn: nn offset, ck: kk offset
    wt[(size_t)(nn0 + rn) * 512 + kk0 + ck] = f2bf(tile[rn][ck]);
  }
}

// ---------- 3) qkv GEMM: [32768x512] @ [512x1536] + bias -> bf16 ----------
__global__ __launch_bounds__(256) void k_gemm_qkv(const unsigned short* __restrict__ A,   // [32768][512]
                                                  const unsigned short* __restrict__ Bt,  // [1536][512]
                                                  const float* __restrict__ bias,         // [1536]
                                                  unsigned short* __restrict__ Cq) {      // [32768][1536]
  const int K = 512, LDA = 512, LDB = 512, LDC = 1536;
  int m0 = blockIdx.x * 128, n0 = blockIdx.y * 128;
  int tid = threadIdx.x;
  int lane = tid & 63, w = tid >> 6;
  int wm = (w & 1) * 64, wn = (w >> 1) * 64;
  int quad = lane >> 4, rr = lane & 15;
  int r8 = lane >> 3, cg = lane & 7;
  int cgs = cg ^ r8;
  const int swz = rr & 7;

  __shared__ __align__(16) unsigned short Als[128][64];
  __shared__ __align__(16) unsigned short Bls[128][64];

  floatx4 acc[4][4];
#pragma unroll
  for (int i = 0; i < 4; i++)
#pragma unroll
    for (int j = 0; j < 4; j++) acc[i][j] = (floatx4){0.f, 0.f, 0.f, 0.f};

  for (int k0 = 0; k0 < K; k0 += 64) {
#pragma unroll
    for (int i = 0; i < 4; i++) {
      int row = i * 32 + w * 8 + r8;
      async_ld16(&Als[i * 32 + w * 8][0], A + (size_t)(m0 + row) * LDA + k0 + cgs * 8);
      async_ld16(&Bls[i * 32 + w * 8][0], Bt + (size_t)(n0 + row) * LDB + k0 + cgs * 8);
    }
    __syncthreads();
#pragma unroll
    for (int kk = 0; kk < 64; kk += 32) {
      int gb = kk >> 3;
      bf16x8 af[4], bfr[4];
#pragma unroll
      for (int mi = 0; mi < 4; mi++)
        af[mi] = *(const bf16x8*)&Als[wm + mi * 16 + rr][(((gb + quad) ^ swz)) * 8];
#pragma unroll
      for (int ni = 0; ni < 4; ni++)
        bfr[ni] = *(const bf16x8*)&Bls[wn + ni * 16 + rr][(((gb + quad) ^ swz)) * 8];
#pragma unroll
      for (int mi = 0; mi < 4; mi++)
#pragma unroll
        for (int ni = 0; ni < 4; ni++)
          acc[mi][ni] = __builtin_amdgcn_mfma_f32_16x16x32_bf16(af[mi], bfr[ni], acc[mi][ni], 0, 0, 0);
    }
    __syncthreads();
  }
#pragma unroll
  for (int ni = 0; ni < 4; ni++) {
    int col = n0 + wn + ni * 16 + rr;
    float bv = bias[col];
#pragma unroll
    for (int mi = 0; mi < 4; mi++) {
      int rbase = m0 + wm + mi * 16 + quad * 4;
#pragma unroll
      for (int r = 0; r < 4; r++)
        Cq[(size_t)(rbase + r) * LDC + col] = f2bf(acc[mi][ni][r] + bv);
    }
  }
}

// ---------- 4) attn logits via MFMA, fused L2-norm. grid (chunk8, h8, b8) ----------
// 8 lanes cover one token's 128B q/k-row contiguously (16 lines/inst, optimal).
// Transposed stage into per-wave LDS [64 dims][40] with tok-group XOR swizzle.
__global__ __launch_bounds__(256) void k_attn(const unsigned short* __restrict__ QKV,
                                              float* __restrict__ logits_p) {
  int chunk = blockIdx.x, hh = blockIdx.y, b = blockIdx.z;
  int tid = threadIdx.x, w = tid >> 6, l = tid & 63;
  int quad = l >> 4, rr = l & 15;

  __shared__ __align__(16) unsigned char smem[65536];
  unsigned short* qT = (unsigned short*)smem + w * 5120;   // 64*40 halfwords
  unsigned short* kT = qT + 2560;
  float* ps = (float*)smem;

  floatx4 acc[4][4];
#pragma unroll
  for (int i = 0; i < 4; i++)
#pragma unroll
    for (int j = 0; j < 4; j++) acc[i][j] = (floatx4){0.f, 0.f, 0.f, 0.f};

  int tok8 = l >> 3;     // token within group of 8
  int seg = l & 7;       // 8-dim segment
  int sw = seg & 3;

  for (int s = 0; s < 4; s++) {
    int nbase = chunk * 512 + w * 128 + s * 32;
#pragma unroll
    for (int c = 0; c < 4; c++) {
      int n = nbase + c * 8 + tok8;
      const unsigned short* p = QKV + (size_t)(b * 4096 + n) * 1536 + hh * 64 + seg * 8;
      uint4 vq = *(const uint4*)p;
      uint4 vk = *(const uint4*)(p + 512);
      unsigned uq[4] = {vq.x, vq.y, vq.z, vq.w};
      unsigned uk[4] = {vk.x, vk.y, vk.z, vk.w};
      float qf[8], kf[8], sq = 0.f, sk = 0.f;
#pragma unroll
      for (int e = 0; e < 4; e++) {
        float2 f = bfp2f(uq[e]); qf[2 * e] = f.x; qf[2 * e + 1] = f.y; sq += f.x * f.x + f.y * f.y;
        float2 g = bfp2f(uk[e]); kf[2 * e] = g.x; kf[2 * e + 1] = g.y; sk += g.x * g.x + g.y * g.y;
      }
      sq += __shfl_xor(sq, 1); sq += __shfl_xor(sq, 2); sq += __shfl_xor(sq, 4);
      sk += __shfl_xor(sk, 1); sk += __shfl_xor(sk, 2); sk += __shfl_xor(sk, 4);
      float scq = 0.125f * rsqrtf(fmaxf(sq, 1e-12f));
      float sck = rsqrtf(fmaxf(sk, 1e-12f));
      int col = ((c ^ sw) << 3) + tok8;
#pragma unroll
      for (int j = 0; j < 8; j++) {
        int dim = seg * 8 + j;
        qT[dim * 40 + col] = f2bf(qf[j] * scq);
        kT[dim * 40 + col] = f2bf(kf[j] * sck);
      }
    }
    bf16x8 af[4], bfr[4];
#pragma unroll
    for (int mi = 0; mi < 4; mi++) {
      int s3 = (mi * 2 + (rr >> 3)) & 3;
      int off = (mi * 16 + rr) * 40 + ((quad ^ s3) << 3);
      af[mi] = *(const bf16x8*)(qT + off);
      bfr[mi] = *(const bf16x8*)(kT + off);
    }
#pragma unroll
    for (int mi = 0; mi < 4; mi++)
#pragma unroll
      for (int ni = 0; ni < 4; ni++)
        acc[mi][ni] = __builtin_amdgcn_mfma_f32_16x16x32_bf16(af[mi], bfr[ni], acc[mi][ni], 0, 0, 0);
  }

  __syncthreads();
#pragma unroll
  for (int mi = 0; mi < 4; mi++)
#pragma unroll
    for (int ni = 0; ni < 4; ni++)
#pragma unroll
      for (int r = 0; r < 4; r++) {
        int d = mi * 16 + quad * 4 + r, e = ni * 16 + rr;
        ps[w * 4096 + d * 64 + e] = acc[mi][ni][r];
      }
  __syncthreads();
  float* outp = logits_p + ((size_t)(b * 8 + hh) * 8 + chunk) * 4096;
  for (int i = tid; i < 4096; i += 256)
    outp[i] = ps[i] + ps[4096 + i] + ps[8192 + i] + ps[12288 + i];
}

// ---------- 5) fused chunk-reduce + softmax + M_b = attn @ w_proj -> Mt bf16 ----------
__global__ __launch_bounds__(256) void k_softmax_m(const float* __restrict__ logits_p,
                                                   const float* __restrict__ wproj,
                                                   unsigned short* __restrict__ Mt) {
  int cc = blockIdx.x, hh = blockIdx.y, b = blockIdx.z;
  int t = threadIdx.x;
  __shared__ float ls[64][64];
  __shared__ float red[64][4];
  __shared__ float inv[64];
  const float* lp = logits_p + (size_t)((b * 8 + hh) * 8) * 4096;
#pragma unroll
  for (int i = 0; i < 16; i++) {
    int id = t + i * 256;
    float s = 0.f;
#pragma unroll
    for (int c = 0; c < 8; c++) s += lp[c * 4096 + id];
    ls[id >> 6][id & 63] = s;
  }
  __syncthreads();
  int row = t >> 2, part = t & 3;
  float mx = -1e30f;
#pragma unroll
  for (int j = 0; j < 16; j++) mx = fmaxf(mx, ls[row][part * 16 + j]);
  red[row][part] = mx;
  __syncthreads();
  if (part == 0) inv[row] = fmaxf(fmaxf(red[row][0], red[row][1]), fmaxf(red[row][2], red[row][3]));
  __syncthreads();
  float rm = inv[row];
  float s = 0.f;
#pragma unroll
  for (int j = 0; j < 16; j++) {
    float e = __expf(ls[row][part * 16 + j] - rm);
    ls[row][part * 16 + j] = e;
    s += e;
  }
  red[row][part] = s;
  __syncthreads();
  if (part == 0) inv[row] = 1.0f / (red[row][0] + red[row][1] + red[row][2] + red[row][3]);
  __syncthreads();

  int cout = cc * 128 + (t & 127);
  int half = t >> 7;
  float wreg[64];
#pragma unroll
  for (int ee = 0; ee < 64; ee++) wreg[ee] = wproj[(size_t)(hh * 64 + ee) * 512 + cout];
  unsigned short ob[32];
#pragma unroll
  for (int d2 = 0; d2 < 32; d2++) {
    int dd = half * 32 + d2;
    float a = 0.f;
#pragma unroll
    for (int e4 = 0; e4 < 16; e4++) {
      float4 p4 = *(const float4*)&ls[dd][e4 * 4];
      a += p4.x * wreg[e4 * 4] + p4.y * wreg[e4 * 4 + 1] + p4.z * wreg[e4 * 4 + 2] + p4.w * wreg[e4 * 4 + 3];
    }
    ob[d2] = f2bf(a * inv[dd]);
  }
  uint4* dst = (uint4*)(Mt + ((size_t)(b * 512 + cout)) * 512 + hh * 64 + half * 32);
#pragma unroll
  for (int i = 0; i < 4; i++) dst[i] = ((const uint4*)ob)[i];
}

// ---------- 6) out GEMM: per b, V[4096x512] @ M_b^T + b_proj -> fp32 ----------
__global__ __launch_bounds__(256) void k_gemm_out(const unsigned short* __restrict__ QKV,
                                                  const unsigned short* __restrict__ MtAll,
                                                  const float* __restrict__ bias,
                                                  float* __restrict__ Out) {
  const int K = 512, LDA = 1536, LDB = 512, LDC = 512;
  int b = blockIdx.x >> 5;
  int m0 = (blockIdx.x & 31) * 128;
  int n0 = blockIdx.y * 128;
  const unsigned short* A = QKV + (size_t)b * NN * 1536 + 1024;  // v slice
  const unsigned short* Bt = MtAll + (size_t)b * 512 * 512;
  int tid = threadIdx.x;
  int lane = tid & 63, w = tid >> 6;
  int wm = (w & 1) * 64, wn = (w >> 1) * 64;
  int quad = lane >> 4, rr = lane & 15;
  int r8 = lane >> 3, cg = lane & 7;
  int cgs = cg ^ r8;
  const int swz = rr & 7;

  __shared__ __align__(16) unsigned short Als[128][64];
  __shared__ __align__(16) unsigned short Bls[128][64];

  floatx4 acc[4][4];
#pragma unroll
  for (int i = 0; i < 4; i++)
#pragma unroll
    for (int j = 0; j < 4; j++) acc[i][j] = (floatx4){0.f, 0.f, 0.f, 0.f};

  for (int k0 = 0; k0 < K; k0 += 64) {
#pragma unroll
    for (int i = 0; i < 4; i++) {
      int row = i * 32 + w * 8 + r8;
      async_ld16(&Als[i * 32 + w * 8][0], A + (size_t)(m0 + row) * LDA + k0 + cgs * 8);
      async_ld16(&Bls[i * 32 + w * 8][0], Bt + (size_t)(n0 + row) * LDB + k0 + cgs * 8);
    }
    __syncthreads();
#pragma unroll
    for (int kk = 0; kk < 64; kk += 32) {
      int gb = kk >> 3;
      bf16x8 af[4], bfr[4];
#pragma unroll
      for (int mi = 0; mi < 4; mi++)
        af[mi] = *(const bf16x8*)&Als[wm + mi * 16 + rr][(((gb + quad) ^ swz)) * 8];
#pragma unroll
      for (int ni = 0; ni < 4; ni++)
        bfr[ni] = *(const bf16x8*)&Bls[wn + ni * 16 + rr][(((gb + quad) ^ swz)) * 8];
#pragma unroll
      for (int mi = 0; mi < 4; mi++)
#pragma unroll
        for (int ni = 0; ni < 4; ni++)
          acc[mi][ni] = __builtin_amdgcn_mfma_f32_16x16x32_bf16(af[mi], bfr[ni], acc[mi][ni], 0, 0, 0);
    }
    __syncthreads();
  }
#pragma unroll
  for (int ni = 0; ni < 4; ni++) {
    int col = n0 + wn + ni * 16 + rr;
    float bv = bias[col];
#pragma unroll
    for (int mi = 0; mi < 4; mi++) {
      int rbase = m0 + wm + mi * 16 + quad * 4;
#pragma unroll
      for (int r = 0; r < 4; r++)
        Out[(size_t)b * NN * LDC + (size_t)(rbase + r) * LDC + col] = acc[mi][ni][r] + bv;
    }
  }
}

extern "C" void kernel_launch(void* const* d_in, const int* in_sizes, int n_in,
                              void* d_out, int out_size, void* d_ws, size_t ws_size,
                              hipStream_t stream) {
  const float* x      = (const float*)d_in[0];
  const float* w_qkv  = (const float*)d_in[1];
  const float* b_qkv  = (const float*)d_in[2];
  const float* w_proj = (const float*)d_in[3];
  const float* b_proj = (const float*)d_in[4];
  float* out = (float*)d_out;

  char* ws = (char*)d_ws;
  size_t off = 0;
  auto alloc = [&](size_t bytes) -> void* {
    void* p = ws + off;
    off += (bytes + 255) & ~(size_t)255;
    return p;
  };
  unsigned short* xb       = (unsigned short*)alloc((size_t)NB * NN * NC * 2);
  unsigned short* wT       = (unsigned short*)alloc((size_t)1536 * 512 * 2);
  unsigned short* qkvb     = (unsigned short*)alloc((size_t)NB * NN * 3 * NC * 2);
  float*          logits_p = (float*)alloc((size_t)NB * NH * 8 * 4096 * 4);
  unsigned short* Mt       = (unsigned short*)alloc((size_t)NB * 512 * 512 * 2);

  k_convert<<<16384, 256, 0, stream>>>(x, xb, NB * NN * NC);
  k_transpose_cvt<<<dim3(24, 8), 256, 0, stream>>>(w_qkv, wT);
  k_gemm_qkv<<<dim3(256, 12), 256, 0, stream>>>(xb, wT, b_qkv, qkvb);
  k_attn<<<dim3(8, 8, 8), 256, 0, stream>>>(qkvb, logits_p);
  k_softmax_m<<<dim3(4, 8, 8), 256, 0, stream>>>(logits_p, w_proj, Mt);
  k_gemm_out<<<dim3(256, 4), 256, 0, stream>>>(qkvb, Mt, b_proj, out);
}

// Round 4
// 268.119 us; speedup vs baseline: 1.4900x; 1.0311x over previous
//
#include <hip/hip_runtime.h>
#include <stdint.h>

// Problem: B=8, N=4096, C=512, H=8, D=64. fp32 in/out, bf16 MFMA internally.
#define NB 8
#define NN 4096
#define NC 512
#define NH 8
#define ATTN_CH 16   // token chunks for k_attn

typedef __bf16 bf16x8 __attribute__((ext_vector_type(8)));
typedef float floatx4 __attribute__((ext_vector_type(4)));

__device__ __forceinline__ unsigned short f2bf(float f) {
  union { float f; unsigned u; } v; v.f = f;
  return (unsigned short)((v.u + 0x7fffu + ((v.u >> 16) & 1u)) >> 16);
}
__device__ __forceinline__ float2 bfp2f(unsigned u) {
  union { unsigned x; float f; } lo, hi;
  lo.x = u << 16; hi.x = u & 0xffff0000u;
  return make_float2(lo.f, hi.f);
}

// async 16B global->LDS (DMA). LDS dest = wave-uniform base + lane*16.
__device__ __forceinline__ void async_ld16(void* lds, const void* g) {
  auto* gp = (const __attribute__((address_space(1))) unsigned int*)(uintptr_t)g;
  auto* lp = (__attribute__((address_space(3))) unsigned int*)(uintptr_t)lds;
  __builtin_amdgcn_global_load_lds(gp, lp, 16, 0, 0);
}

// ---------- 1) fused: x fp32->bf16 convert  +  w_qkv transpose->bf16 ----------
__global__ __launch_bounds__(256) void k_prep(const float* __restrict__ x,
                                              unsigned short* __restrict__ xb,
                                              const float* __restrict__ w,
                                              unsigned short* __restrict__ wt) {
  int bid = blockIdx.x;
  if (bid < 16384) {
    int i = (bid * 256 + threadIdx.x) * 4;
    float4 v = *(const float4*)(x + i);
    ushort4 o;
    o.x = f2bf(v.x); o.y = f2bf(v.y); o.z = f2bf(v.z); o.w = f2bf(v.w);
    *(ushort4*)(xb + i) = o;
    return;
  }
  // transpose 64x64 tile of w [512][1536] -> wt [1536][512]
  __shared__ float tile[64][65];
  int b2 = bid - 16384;                  // 0..191
  int nn0 = (b2 % 24) * 64, kk0 = (b2 / 24) * 64;
  int t = threadIdx.x;
#pragma unroll
  for (int i = 0; i < 16; i++) {
    int id = t + i * 256;
    int r = id >> 6, c = id & 63;
    tile[c][r] = w[(size_t)(kk0 + r) * 1536 + nn0 + c];
  }
  __syncthreads();
#pragma unroll
  for (int i = 0; i < 16; i++) {
    int id = t + i * 256;
    int rn = id >> 6, ck = id & 63;
    wt[(size_t)(nn0 + rn) * 512 + kk0 + ck] = f2bf(tile[rn][ck]);
  }
}

// ---------- 2) qkv GEMM: [32768x512] @ [512x1536] + bias -> bf16 ----------
// XCD-aware swizzle: all 12 n-tiles of an m-tile on one XCD, adjacent ids ->
// A-tile fetched from L3 once per m-tile, B panel L2-resident per XCD.
__global__ __launch_bounds__(256) void k_gemm_qkv(const unsigned short* __restrict__ A,   // [32768][512]
                                                  const unsigned short* __restrict__ Bt,  // [1536][512]
                                                  const float* __restrict__ bias,         // [1536]
                                                  unsigned short* __restrict__ Cq) {      // [32768][1536]
  const int K = 512, LDA = 512, LDB = 512, LDC = 1536;
  int bid = blockIdx.x;
  int xcd = bid & 7, local = bid >> 3;
  int mloc = local / 12, nt = local - mloc * 12;
  int m0 = (xcd * 32 + mloc) * 128, n0 = nt * 128;

  int tid = threadIdx.x;
  int lane = tid & 63, w = tid >> 6;
  int wm = (w & 1) * 64, wn = (w >> 1) * 64;
  int quad = lane >> 4, rr = lane & 15;
  int r8 = lane >> 3, cg = lane & 7;
  int cgs = cg ^ r8;
  const int swz = rr & 7;

  __shared__ __align__(16) unsigned short Als[128][64];
  __shared__ __align__(16) unsigned short Bls[128][64];

  floatx4 acc[4][4];
#pragma unroll
  for (int i = 0; i < 4; i++)
#pragma unroll
    for (int j = 0; j < 4; j++) acc[i][j] = (floatx4){0.f, 0.f, 0.f, 0.f};

  for (int k0 = 0; k0 < K; k0 += 64) {
#pragma unroll
    for (int i = 0; i < 4; i++) {
      int row = i * 32 + w * 8 + r8;
      async_ld16(&Als[i * 32 + w * 8][0], A + (size_t)(m0 + row) * LDA + k0 + cgs * 8);
      async_ld16(&Bls[i * 32 + w * 8][0], Bt + (size_t)(n0 + row) * LDB + k0 + cgs * 8);
    }
    __syncthreads();
#pragma unroll
    for (int kk = 0; kk < 64; kk += 32) {
      int gb = kk >> 3;
      bf16x8 af[4], bfr[4];
#pragma unroll
      for (int mi = 0; mi < 4; mi++)
        af[mi] = *(const bf16x8*)&Als[wm + mi * 16 + rr][(((gb + quad) ^ swz)) * 8];
#pragma unroll
      for (int ni = 0; ni < 4; ni++)
        bfr[ni] = *(const bf16x8*)&Bls[wn + ni * 16 + rr][(((gb + quad) ^ swz)) * 8];
#pragma unroll
      for (int mi = 0; mi < 4; mi++)
#pragma unroll
        for (int ni = 0; ni < 4; ni++)
          acc[mi][ni] = __builtin_amdgcn_mfma_f32_16x16x32_bf16(af[mi], bfr[ni], acc[mi][ni], 0, 0, 0);
    }
    __syncthreads();
  }
#pragma unroll
  for (int ni = 0; ni < 4; ni++) {
    int col = n0 + wn + ni * 16 + rr;
    float bv = bias[col];
#pragma unroll
    for (int mi = 0; mi < 4; mi++) {
      int rbase = m0 + wm + mi * 16 + quad * 4;
#pragma unroll
      for (int r = 0; r < 4; r++)
        Cq[(size_t)(rbase + r) * LDC + col] = f2bf(acc[mi][ni][r] + bv);
    }
  }
}

// ---------- 3) attn logits via MFMA, fused L2-norm. grid (chunk16, h8, b8) ----------
// 8 lanes cover one token's 128B row contiguously; per-wave transposed LDS tiles.
__global__ __launch_bounds__(256) void k_attn(const unsigned short* __restrict__ QKV,
                                              float* __restrict__ logits_p) {
  int chunk = blockIdx.x, hh = blockIdx.y, b = blockIdx.z;
  int tid = threadIdx.x, w = tid >> 6, l = tid & 63;
  int quad = l >> 4, rr = l & 15;

  __shared__ __align__(16) unsigned char smem[40960];
  unsigned short* qT = (unsigned short*)smem + w * 5120;   // 64*40 halfwords
  unsigned short* kT = qT + 2560;
  float* ps = (float*)smem;                                 // 16KB, reused after barrier

  floatx4 acc[4][4];
#pragma unroll
  for (int i = 0; i < 4; i++)
#pragma unroll
    for (int j = 0; j < 4; j++) acc[i][j] = (floatx4){0.f, 0.f, 0.f, 0.f};

  int tok8 = l >> 3;
  int seg = l & 7;
  int sw = seg & 3;

  for (int s = 0; s < 2; s++) {
    int nbase = chunk * 256 + w * 64 + s * 32;
#pragma unroll
    for (int c = 0; c < 4; c++) {
      int n = nbase + c * 8 + tok8;
      const unsigned short* p = QKV + (size_t)(b * 4096 + n) * 1536 + hh * 64 + seg * 8;
      uint4 vq = *(const uint4*)p;
      uint4 vk = *(const uint4*)(p + 512);
      unsigned uq[4] = {vq.x, vq.y, vq.z, vq.w};
      unsigned uk[4] = {vk.x, vk.y, vk.z, vk.w};
      float qf[8], kf[8], sq = 0.f, sk = 0.f;
#pragma unroll
      for (int e = 0; e < 4; e++) {
        float2 f = bfp2f(uq[e]); qf[2 * e] = f.x; qf[2 * e + 1] = f.y; sq += f.x * f.x + f.y * f.y;
        float2 g = bfp2f(uk[e]); kf[2 * e] = g.x; kf[2 * e + 1] = g.y; sk += g.x * g.x + g.y * g.y;
      }
      sq += __shfl_xor(sq, 1); sq += __shfl_xor(sq, 2); sq += __shfl_xor(sq, 4);
      sk += __shfl_xor(sk, 1); sk += __shfl_xor(sk, 2); sk += __shfl_xor(sk, 4);
      float scq = 0.125f * rsqrtf(fmaxf(sq, 1e-12f));
      float sck = rsqrtf(fmaxf(sk, 1e-12f));
      int col = ((c ^ sw) << 3) + tok8;
#pragma unroll
      for (int j = 0; j < 8; j++) {
        int dim = seg * 8 + j;
        qT[dim * 40 + col] = f2bf(qf[j] * scq);
        kT[dim * 40 + col] = f2bf(kf[j] * sck);
      }
    }
    bf16x8 af[4], bfr[4];
#pragma unroll
    for (int mi = 0; mi < 4; mi++) {
      int s3 = (mi * 2 + (rr >> 3)) & 3;
      int off = (mi * 16 + rr) * 40 + ((quad ^ s3) << 3);
      af[mi] = *(const bf16x8*)(qT + off);
      bfr[mi] = *(const bf16x8*)(kT + off);
    }
#pragma unroll
    for (int mi = 0; mi < 4; mi++)
#pragma unroll
      for (int ni = 0; ni < 4; ni++)
        acc[mi][ni] = __builtin_amdgcn_mfma_f32_16x16x32_bf16(af[mi], bfr[ni], acc[mi][ni], 0, 0, 0);
  }

  __syncthreads();  // staging tiles dead; ps takes over first 16KB
  for (int r2 = 0; r2 < 4; r2++) {
    if (w == r2) {
#pragma unroll
      for (int mi = 0; mi < 4; mi++)
#pragma unroll
        for (int ni = 0; ni < 4; ni++)
#pragma unroll
          for (int r = 0; r < 4; r++) {
            int d = mi * 16 + quad * 4 + r, e = ni * 16 + rr;
            if (r2 == 0) ps[d * 64 + e] = acc[mi][ni][r];
            else         ps[d * 64 + e] += acc[mi][ni][r];
          }
    }
    __syncthreads();
  }
  float* outp = logits_p + ((size_t)(b * 8 + hh) * ATTN_CH + chunk) * 4096;
  for (int i = tid; i < 4096; i += 256) outp[i] = ps[i];
}

// ---------- 4) fused chunk-reduce + softmax + M_b = attn @ w_proj -> Mt bf16 ----------
// grid (cc4 x rowhalf2, h8, b8): block does 32 rows x 128 couts.
__global__ __launch_bounds__(256) void k_softmax_m(const float* __restrict__ logits_p,
                                                   const float* __restrict__ wproj,
                                                   unsigned short* __restrict__ Mt) {
  int cc = blockIdx.x & 3, rh = blockIdx.x >> 2;
  int hh = blockIdx.y, b = blockIdx.z;
  int t = threadIdx.x;
  __shared__ float ls[32][64];
  __shared__ float red[32][8];
  __shared__ float inv[32];
  const float* lp = logits_p + (size_t)((b * 8 + hh) * ATTN_CH) * 4096 + rh * 2048;
#pragma unroll
  for (int i = 0; i < 8; i++) {
    int id = t + i * 256;               // 0..2047 over [32 rows][64]
    float s = 0.f;
#pragma unroll
    for (int c = 0; c < ATTN_CH; c++) s += lp[c * 4096 + id];
    ls[id >> 6][id & 63] = s;
  }
  __syncthreads();
  int row = t >> 3, part = t & 7;       // 8 threads per row
  float mx = -1e30f;
#pragma unroll
  for (int j = 0; j < 8; j++) mx = fmaxf(mx, ls[row][part * 8 + j]);
  red[row][part] = mx;
  __syncthreads();
  if (part == 0) {
    float m2 = red[row][0];
#pragma unroll
    for (int j = 1; j < 8; j++) m2 = fmaxf(m2, red[row][j]);
    inv[row] = m2;
  }
  __syncthreads();
  float rm = inv[row];
  float s = 0.f;
#pragma unroll
  for (int j = 0; j < 8; j++) {
    float e = __expf(ls[row][part * 8 + j] - rm);
    ls[row][part * 8 + j] = e;
    s += e;
  }
  red[row][part] = s;
  __syncthreads();
  if (part == 0) {
    float s2 = 0.f;
#pragma unroll
    for (int j = 0; j < 8; j++) s2 += red[row][j];
    inv[row] = 1.0f / s2;
  }
  __syncthreads();

  int cout = cc * 128 + (t & 127);
  int half = t >> 7;                    // 0..1 -> 16 rows each
  float wreg[64];
#pragma unroll
  for (int ee = 0; ee < 64; ee++) wreg[ee] = wproj[(size_t)(hh * 64 + ee) * 512 + cout];
  unsigned short ob[16];
#pragma unroll
  for (int d2 = 0; d2 < 16; d2++) {
    int dd = half * 16 + d2;            // local row 0..31
    float a = 0.f;
#pragma unroll
    for (int e4 = 0; e4 < 16; e4++) {
      float4 p4 = *(const float4*)&ls[dd][e4 * 4];
      a += p4.x * wreg[e4 * 4] + p4.y * wreg[e4 * 4 + 1] + p4.z * wreg[e4 * 4 + 2] + p4.w * wreg[e4 * 4 + 3];
    }
    ob[d2] = f2bf(a * inv[dd]);
  }
  uint4* dst = (uint4*)(Mt + ((size_t)(b * 512 + cout)) * 512 + hh * 64 + rh * 32 + half * 16);
  dst[0] = ((const uint4*)ob)[0];
  dst[1] = ((const uint4*)ob)[1];
}

// ---------- 5) out GEMM: per b, V[4096x512] @ M_b^T + b_proj -> fp32 ----------
// XCD swizzle: 4 n-tiles of an m-tile adjacent on one XCD.
__global__ __launch_bounds__(256) void k_gemm_out(const unsigned short* __restrict__ QKV,
                                                  const unsigned short* __restrict__ MtAll,
                                                  const float* __restrict__ bias,
                                                  float* __restrict__ Out) {
  const int K = 512, LDA = 1536, LDB = 512, LDC = 512;
  int bid = blockIdx.x;
  int xcd = bid & 7, local = bid >> 3;
  int mloc = local >> 2, nt = local & 3;
  int g = xcd * 32 + mloc;
  int b = g >> 5;
  int m0 = (g & 31) * 128;
  int n0 = nt * 128;
  const unsigned short* A = QKV + (size_t)b * NN * 1536 + 1024;  // v slice
  const unsigned short* Bt = MtAll + (size_t)b * 512 * 512;
  int tid = threadIdx.x;
  int lane = tid & 63, w = tid >> 6;
  int wm = (w & 1) * 64, wn = (w >> 1) * 64;
  int quad = lane >> 4, rr = lane & 15;
  int r8 = lane >> 3, cg = lane & 7;
  int cgs = cg ^ r8;
  const int swz = rr & 7;

  __shared__ __align__(16) unsigned short Als[128][64];
  __shared__ __align__(16) unsigned short Bls[128][64];

  floatx4 acc[4][4];
#pragma unroll
  for (int i = 0; i < 4; i++)
#pragma unroll
    for (int j = 0; j < 4; j++) acc[i][j] = (floatx4){0.f, 0.f, 0.f, 0.f};

  for (int k0 = 0; k0 < K; k0 += 64) {
#pragma unroll
    for (int i = 0; i < 4; i++) {
      int row = i * 32 + w * 8 + r8;
      async_ld16(&Als[i * 32 + w * 8][0], A + (size_t)(m0 + row) * LDA + k0 + cgs * 8);
      async_ld16(&Bls[i * 32 + w * 8][0], Bt + (size_t)(n0 + row) * LDB + k0 + cgs * 8);
    }
    __syncthreads();
#pragma unroll
    for (int kk = 0; kk < 64; kk += 32) {
      int gb = kk >> 3;
      bf16x8 af[4], bfr[4];
#pragma unroll
      for (int mi = 0; mi < 4; mi++)
        af[mi] = *(const bf16x8*)&Als[wm + mi * 16 + rr][(((gb + quad) ^ swz)) * 8];
#pragma unroll
      for (int ni = 0; ni < 4; ni++)
        bfr[ni] = *(const bf16x8*)&Bls[wn + ni * 16 + rr][(((gb + quad) ^ swz)) * 8];
#pragma unroll
      for (int mi = 0; mi < 4; mi++)
#pragma unroll
        for (int ni = 0; ni < 4; ni++)
          acc[mi][ni] = __builtin_amdgcn_mfma_f32_16x16x32_bf16(af[mi], bfr[ni], acc[mi][ni], 0, 0, 0);
    }
    __syncthreads();
  }
#pragma unroll
  for (int ni = 0; ni < 4; ni++) {
    int col = n0 + wn + ni * 16 + rr;
    float bv = bias[col];
#pragma unroll
    for (int mi = 0; mi < 4; mi++) {
      int rbase = m0 + wm + mi * 16 + quad * 4;
#pragma unroll
      for (int r = 0; r < 4; r++)
        Out[(size_t)b * NN * LDC + (size_t)(rbase + r) * LDC + col] = acc[mi][ni][r] + bv;
    }
  }
}

extern "C" void kernel_launch(void* const* d_in, const int* in_sizes, int n_in,
                              void* d_out, int out_size, void* d_ws, size_t ws_size,
                              hipStream_t stream) {
  const float* x      = (const float*)d_in[0];
  const float* w_qkv  = (const float*)d_in[1];
  const float* b_qkv  = (const float*)d_in[2];
  const float* w_proj = (const float*)d_in[3];
  const float* b_proj = (const float*)d_in[4];
  float* out = (float*)d_out;

  char* ws = (char*)d_ws;
  size_t off = 0;
  auto alloc = [&](size_t bytes) -> void* {
    void* p = ws + off;
    off += (bytes + 255) & ~(size_t)255;
    return p;
  };
  unsigned short* xb       = (unsigned short*)alloc((size_t)NB * NN * NC * 2);
  unsigned short* wT       = (unsigned short*)alloc((size_t)1536 * 512 * 2);
  unsigned short* qkvb     = (unsigned short*)alloc((size_t)NB * NN * 3 * NC * 2);
  float*          logits_p = (float*)alloc((size_t)NB * NH * ATTN_CH * 4096 * 4);
  unsigned short* Mt       = (unsigned short*)alloc((size_t)NB * 512 * 512 * 2);

  k_prep<<<16576, 256, 0, stream>>>(x, xb, w_qkv, wT);
  k_gemm_qkv<<<3072, 256, 0, stream>>>(xb, wT, b_qkv, qkvb);
  k_attn<<<dim3(ATTN_CH, 8, 8), 256, 0, stream>>>(qkvb, logits_p);
  k_softmax_m<<<dim3(8, 8, 8), 256, 0, stream>>>(logits_p, w_proj, Mt);
  k_gemm_out<<<1024, 256, 0, stream>>>(qkvb, Mt, b_proj, out);
}